// Round 1
// baseline (75.432 us; speedup 1.0000x reference)
//
#include <hip/hip_runtime.h>
#include <math.h>

// TropConv2D: out[b,i,j,f] = max_k(p[b,i,j,k] + w[k,f]) - min_k(...) + bias[f]
// k = (ki*3 + kj)*32 + c over a 3x3 spatial window, C=32 channels.
// x: [8,32,32,32] f32, w: [288,64] f32, bias: [64] f32, out: [8,30,30,64] f32.

#define COLP 36  // padded col dim: multiple of 4 (16B align for float4 LDS reads)

__global__ __launch_bounds__(256) void trop_kernel(
    const float* __restrict__ x, const float* __restrict__ w,
    const float* __restrict__ bias, float* __restrict__ out) {
  __shared__ float wl[96 * 64];        // one ki-slice of w: 24 KB
  __shared__ float xt[3 * 32 * COLP];  // x rows i..i+2 transposed [ki][c][col]: 13.8 KB

  const int b = blockIdx.x / 30;
  const int i = blockIdx.x % 30;
  const int tid = threadIdx.x;
  const int f = tid & 63;        // lane = filter
  const int wave = tid >> 6;     // wave = pixel group
  const int j0 = wave * 8;       // first output column for this wave

  float mx[8], mn[8];
#pragma unroll
  for (int p = 0; p < 8; ++p) { mx[p] = -INFINITY; mn[p] = INFINITY; }

  // ---- stage x rows i..i+2 into LDS, transposed to [ki][c][col] ----
  // 3*32*32 = 3072 floats = 768 float4 loads; 3 per thread.
  const float* xb = x + (((size_t)b * 32 + i) * 32) * 32;  // start of row i
#pragma unroll
  for (int t = 0; t < 3; ++t) {
    int idx = tid + t * 256;       // 0..767
    int ki = idx >> 8;             // 0..2
    int rem = idx & 255;
    int col = rem >> 3;            // 0..31
    int c4 = (rem & 7) * 4;        // 0,4,...,28
    float4 v = *(const float4*)(xb + ((size_t)(ki * 32 + col)) * 32 + c4);
    float* dst = &xt[(ki * 32 + c4) * COLP + col];
    dst[0 * COLP] = v.x;
    dst[1 * COLP] = v.y;
    dst[2 * COLP] = v.z;
    dst[3 * COLP] = v.w;
  }

  for (int ki = 0; ki < 3; ++ki) {
    __syncthreads();  // protect wl from overwrite while prior slice in use
    // ---- stage w ki-slice: 96*64 floats = 1536 float4; 6 per thread ----
    const float4* wg = (const float4*)(w + ki * 96 * 64);
    float4* wld = (float4*)wl;
#pragma unroll
    for (int t = 0; t < 6; ++t) {
      wld[tid + t * 256] = wg[tid + t * 256];
    }
    __syncthreads();

#pragma unroll
    for (int c = 0; c < 32; ++c) {
      const float* row = &xt[(ki * 32 + c) * COLP];
      float4 a = *(const float4*)(row + j0);
      float4 bq = *(const float4*)(row + j0 + 4);
      float4 cq = *(const float4*)(row + j0 + 8);
      float xr[12] = {a.x, a.y, a.z, a.w, bq.x, bq.y, bq.z, bq.w,
                      cq.x, cq.y, cq.z, cq.w};
#pragma unroll
      for (int kj = 0; kj < 3; ++kj) {
        float wval = wl[(kj * 32 + c) * 64 + f];
#pragma unroll
        for (int p = 0; p < 8; ++p) {
          float t2 = xr[p + kj] + wval;
          mx[p] = fmaxf(mx[p], t2);
          mn[p] = fminf(mn[p], t2);
        }
      }
    }
  }

  // ---- epilogue ----
  float bv = bias[f];
  float* ob = out + (((size_t)b * 30 + i) * 30) * 64 + f;
#pragma unroll
  for (int p = 0; p < 8; ++p) {
    int j = j0 + p;
    if (j < 30) ob[(size_t)j * 64] = mx[p] - mn[p] + bv;
  }
}

extern "C" void kernel_launch(void* const* d_in, const int* in_sizes, int n_in,
                              void* d_out, int out_size, void* d_ws, size_t ws_size,
                              hipStream_t stream) {
  const float* x = (const float*)d_in[0];
  const float* w = (const float*)d_in[1];
  const float* bias = (const float*)d_in[2];
  float* out = (float*)d_out;
  dim3 grid(8 * 30);   // one block per (batch, output row)
  dim3 block(256);     // 4 waves: lane = filter, wave = 8-column pixel group
  hipLaunchKernelGGL(trop_kernel, grid, block, 0, stream, x, w, bias, out);
}

// Round 2
// 71.777 us; speedup vs baseline: 1.0509x; 1.0509x over previous
//
#include <hip/hip_runtime.h>
#include <math.h>

// TropConv2D: out[b,i,j,f] = max_k(p[k] + w[k,f]) - min_k(p[k] + w[k,f]) + bias[f]
// k = (ki*3 + kj)*32 + c, 3x3 window, C=32, F=64.
// x: [8,32,32,32] f32, w: [288,64] f32, bias: [64] f32, out: [8,30,30,64] f32.
//
// Block = 256 thr = 4 waves, covers (b, i, jgroup of 8 cols). lane = filter f,
// wave = 2-column pixel pair. Grid 960 blocks -> ~15 waves/CU (vs 4 in R0).

#define NCOL 10  // staged local cols: 8 outputs + 2 halo

__global__ __launch_bounds__(256) void trop_kernel(
    const float* __restrict__ x, const float* __restrict__ w,
    const float* __restrict__ bias, float* __restrict__ out) {
  __shared__ float wl[96 * 64];        // 24 KB: one ki-slice of w [kj*32+c][f]
  __shared__ float xt[3 * 32 * NCOL];  // 3.75 KB: x transposed [ki][c][col]

  const int jg = blockIdx.x;  // 0..3 column group
  const int i = blockIdx.y;   // 0..29 output row
  const int b = blockIdx.z;   // 0..7 batch
  const int tid = threadIdx.x;
  const int f = tid & 63;     // lane = filter
  const int wave = tid >> 6;  // wave = column pair
  const int jw = wave * 2;    // local col base within tile
  const int j0 = jg * 8;      // global col base of tile

  // ---- stage x rows i..i+2, cols j0..min(j0+9,31), transposed [ki][c][col] ----
  // 30 (ki,col) pairs x 8 float4 each = 240 float4 loads, 1 per thread.
  const float* xb = x + (((size_t)b * 32 + i) * 32) * 32;
  if (tid < 240) {
    int ki = tid / 80;
    int rem = tid % 80;
    int col = rem / 8;         // 0..9 local
    int c4 = (rem % 8) * 4;    // 0,4,...,28
    if (j0 + col < 32) {       // clip at image edge (jg=3 tile extends past W)
      float4 v = *(const float4*)(xb + ((size_t)(ki * 32 + j0 + col)) * 32 + c4);
      xt[(ki * 32 + c4 + 0) * NCOL + col] = v.x;
      xt[(ki * 32 + c4 + 1) * NCOL + col] = v.y;
      xt[(ki * 32 + c4 + 2) * NCOL + col] = v.z;
      xt[(ki * 32 + c4 + 3) * NCOL + col] = v.w;
    }
  }

  float mx0 = -INFINITY, mx1 = -INFINITY;
  float mn0 = INFINITY, mn1 = INFINITY;

  for (int ki = 0; ki < 3; ++ki) {
    __syncthreads();  // protect wl reuse (and x writes->reads on ki=0)
    // ---- stage w ki-slice: 6144 floats = 1536 float4, 6 per thread ----
    const float4* wg = (const float4*)(w + ki * 96 * 64);
    float4* wld = (float4*)wl;
#pragma unroll
    for (int t = 0; t < 6; ++t) wld[tid + t * 256] = wg[tid + t * 256];
    __syncthreads();

#pragma unroll
    for (int c = 0; c < 32; ++c) {
      // x: wave-uniform broadcast reads, immediate offsets
      const float* row = &xt[(ki * 32 + c) * NCOL];
      float2 a = *(const float2*)(row + jw);      // cols jw, jw+1
      float2 d = *(const float2*)(row + jw + 2);  // cols jw+2, jw+3
      // w: lanes f=0..63 consecutive -> conflict-free
      float w0 = wl[(0 * 32 + c) * 64 + f];
      float w1 = wl[(1 * 32 + c) * 64 + f];
      float w2 = wl[(2 * 32 + c) * 64 + f];
      float t00 = a.x + w0, t01 = a.y + w0;
      float t10 = a.y + w1, t11 = d.x + w1;
      float t20 = d.x + w2, t21 = d.y + w2;
      mx0 = fmaxf(mx0, fmaxf(t00, fmaxf(t10, t20)));
      mx1 = fmaxf(mx1, fmaxf(t01, fmaxf(t11, t21)));
      mn0 = fminf(mn0, fminf(t00, fminf(t10, t20)));
      mn1 = fminf(mn1, fminf(t01, fminf(t11, t21)));
    }
  }

  // ---- epilogue: lanes f consecutive -> coalesced 256B stores ----
  float bv = bias[f];
  float* ob = out + (((size_t)b * 30 + i) * 30) * 64 + f;
  int j = j0 + jw;
  if (j < 30) ob[(size_t)j * 64] = mx0 - mn0 + bv;
  if (j + 1 < 30) ob[(size_t)(j + 1) * 64] = mx1 - mn1 + bv;
}

extern "C" void kernel_launch(void* const* d_in, const int* in_sizes, int n_in,
                              void* d_out, int out_size, void* d_ws, size_t ws_size,
                              hipStream_t stream) {
  const float* x = (const float*)d_in[0];
  const float* w = (const float*)d_in[1];
  const float* bias = (const float*)d_in[2];
  float* out = (float*)d_out;
  dim3 grid(4, 30, 8);  // (jgroup, row, batch) = 960 blocks
  dim3 block(256);
  hipLaunchKernelGGL(trop_kernel, grid, block, 0, stream, x, w, bias, out);
}

// Round 3
// 69.599 us; speedup vs baseline: 1.0838x; 1.0313x over previous
//
#include <hip/hip_runtime.h>
#include <math.h>

// TropConv2D: out[b,i,j,f] = max_k(p[k]+w[k,f]) - min_k(p[k]+w[k,f]) + bias[f]
// k = (ki*3+kj)*32+c, 3x3 window, C=32, F=64.
// x: [8,32,32,32] f32, w: [288,64] f32, bias: [64] f32, out: [8,30,30,64] f32.
//
// R3: lane = filter f, wave = 4 output columns. w staged in LDS per-ki slice
// ([k][f] layout, lanes consecutive -> conflict-free). x read directly from
// global with wave-uniform (readfirstlane'd) addresses -> SMEM/L2 path,
// zero LDS traffic for x. Grid 480 blocks (~8 waves/CU).

__global__ __launch_bounds__(256) void trop_kernel(
    const float* __restrict__ x, const float* __restrict__ w,
    const float* __restrict__ bias, float* __restrict__ out) {
  __shared__ float wl[96 * 64];  // 24 KB: one ki-slice of w, [kj*32+c][f]

  const int jg = blockIdx.x;  // 0..1 column group (bases 0, 14; 2-col overlap)
  const int i = blockIdx.y;   // 0..29 output row
  const int b = blockIdx.z;   // 0..7 batch
  const int tid = threadIdx.x;
  const int f = tid & 63;     // lane = filter
  // wave-uniform column base (readfirstlane so the compiler can scalarize
  // all x addressing -> s_load instead of LDS/vector loads)
  const int jwu = __builtin_amdgcn_readfirstlane(tid >> 6) * 4;
  const int j0 = jg * 14 + jwu;  // first output col of this wave; j0+3 <= 29

  float mx[4] = {-INFINITY, -INFINITY, -INFINITY, -INFINITY};
  float mn[4] = {INFINITY, INFINITY, INFINITY, INFINITY};

  for (int ki = 0; ki < 3; ++ki) {
    __syncthreads();  // protect wl from overwrite while prior slice in use
    // stage w ki-slice: 6144 floats = 1536 float4, 6 per thread, coalesced
    const float4* wg = (const float4*)(w + ki * 96 * 64);
    float4* wld = (float4*)wl;
#pragma unroll
    for (int t = 0; t < 6; ++t) wld[tid + t * 256] = wg[tid + t * 256];
    __syncthreads();

    // x row for (b, i+ki), starting at wave-uniform column j0
    const float* xr = x + (((size_t)b * 32 + (i + ki)) * 32 + j0) * 32;

#pragma unroll
    for (int c8 = 0; c8 < 32; c8 += 8) {
      // 6 columns x 8 channels, wave-uniform addresses
      float4 xa[6][2];
#pragma unroll
      for (int col = 0; col < 6; ++col) {
        xa[col][0] = *(const float4*)(xr + col * 32 + c8);
        xa[col][1] = *(const float4*)(xr + col * 32 + c8 + 4);
      }
      const float* wbase = &wl[c8 * 64 + f];
#pragma unroll
      for (int c = 0; c < 8; ++c) {
        float w0 = wbase[c * 64];            // kj=0
        float w1 = wbase[32 * 64 + c * 64];  // kj=1
        float w2 = wbase[64 * 64 + c * 64];  // kj=2
        float xv[6];
#pragma unroll
        for (int col = 0; col < 6; ++col)
          xv[col] = ((const float*)xa[col])[c];  // const idx after unroll
#pragma unroll
        for (int p = 0; p < 4; ++p) {
          float a0 = xv[p + 0] + w0;
          float a1 = xv[p + 1] + w1;
          float a2 = xv[p + 2] + w2;
          mx[p] = fmaxf(mx[p], fmaxf(a0, fmaxf(a1, a2)));
          mn[p] = fminf(mn[p], fminf(a0, fminf(a1, a2)));
        }
      }
    }
  }

  // epilogue: lanes f consecutive -> coalesced 256 B stores; cols 14,15 are
  // written by both jg groups with identical values (benign)
  float bv = bias[f];
  float* ob = out + (((size_t)b * 30 + i) * 30 + j0) * 64 + f;
#pragma unroll
  for (int p = 0; p < 4; ++p) ob[p * 64] = mx[p] - mn[p] + bv;
}

extern "C" void kernel_launch(void* const* d_in, const int* in_sizes, int n_in,
                              void* d_out, int out_size, void* d_ws, size_t ws_size,
                              hipStream_t stream) {
  const float* x = (const float*)d_in[0];
  const float* w = (const float*)d_in[1];
  const float* bias = (const float*)d_in[2];
  float* out = (float*)d_out;
  dim3 grid(2, 30, 8);  // (col-group, row, batch) = 480 blocks
  dim3 block(256);      // 4 waves: lane = filter, wave = 4 columns
  hipLaunchKernelGGL(trop_kernel, grid, block, 0, stream, x, w, bias, out);
}

// Round 4
// 68.433 us; speedup vs baseline: 1.1023x; 1.0170x over previous
//
#include <hip/hip_runtime.h>
#include <math.h>

// TropConv2D: out[b,i,j,f] = max_k(p[k]+w[k,f]) - min_k(p[k]+w[k,f]) + bias[f]
// k = (ki*3+kj)*32+c, 3x3 window, C=32, F=64.
// x: [8,32,32,32] f32, w: [288,64] f32, bias: [64] f32, out: [8,30,30,64] f32.
//
// R4: block = 512 thr = 8 waves = one (b, i) output row; wave = 4 cols, lane = f.
// w staged per-ki TRANSPOSED in LDS as wt[f][kk] (stride 100: 16B-aligned rows,
// bank-balanced b128 reads: lane f reads its own row -> 24 b128/ki vs 96 b32).
// x read via wave-uniform (readfirstlane) addresses -> scalar/SMEM path.

#define WSTRIDE 100  // 96 k-values + 4 pad; %32==4 -> balanced banks, 16B rows

__global__ __launch_bounds__(512) void trop_kernel(
    const float* __restrict__ x, const float* __restrict__ w,
    const float* __restrict__ bias, float* __restrict__ out) {
  __shared__ float wt[64 * WSTRIDE];  // 25.6 KB: one ki-slice, transposed [f][kk]

  const int i = blockIdx.x;  // 0..29 output row
  const int b = blockIdx.y;  // 0..7 batch
  const int tid = threadIdx.x;
  const int f = tid & 63;  // lane = filter
  // wave-uniform column base: waves 0..7 -> cols 0,4,...,28 (wave 7: 2 valid)
  const int j0 = __builtin_amdgcn_readfirstlane(tid >> 6) * 4;

  // staging decomposition: thread covers (f, k-quad)
  const int skq = tid >> 6;  // 0..7

  float mx[4] = {-INFINITY, -INFINITY, -INFINITY, -INFINITY};
  float mn[4] = {INFINITY, INFINITY, INFINITY, INFINITY};
  float bv = bias[f];

  for (int ki = 0; ki < 3; ++ki) {
    __syncthreads();  // protect wt from overwrite while prior slice in use
    // ---- stage w ki-slice transposed: wt[f][kk] = w[ki*96+kk][f] ----
    // per thread: 3 quads of kk -> 12 coalesced global b32 + 3 ds_write_b128
#pragma unroll
    for (int it = 0; it < 3; ++it) {
      int k0 = (it * 8 + skq) * 4;  // 0..92, step 4
      float4 v;
      v.x = w[(ki * 96 + k0 + 0) * 64 + f];
      v.y = w[(ki * 96 + k0 + 1) * 64 + f];
      v.z = w[(ki * 96 + k0 + 2) * 64 + f];
      v.w = w[(ki * 96 + k0 + 3) * 64 + f];
      *(float4*)(&wt[f * WSTRIDE + k0]) = v;
    }
    __syncthreads();

    // x row for (b, i+ki); wave-uniform column addresses, clamped at edge
    const float* xr = x + (((size_t)b * 32 + (i + ki)) * 32) * 32;
    int cc[6];
#pragma unroll
    for (int col = 0; col < 6; ++col) cc[col] = (j0 + col < 32) ? j0 + col : 31;

#pragma unroll
    for (int c8 = 0; c8 < 32; c8 += 8) {
      // x: 6 cols x 8 channels, uniform -> scalar loads
      float4 xa[6][2];
#pragma unroll
      for (int col = 0; col < 6; ++col) {
        xa[col][0] = *(const float4*)(xr + cc[col] * 32 + c8);
        xa[col][1] = *(const float4*)(xr + cc[col] * 32 + c8 + 4);
      }
      // w: lane f's own row, 3 kj-rows x 8 channels via b128
      float4 wv[3][2];
#pragma unroll
      for (int kj = 0; kj < 3; ++kj) {
        const float* wrow = &wt[f * WSTRIDE + kj * 32 + c8];
        wv[kj][0] = *(const float4*)(wrow);
        wv[kj][1] = *(const float4*)(wrow + 4);
      }
#pragma unroll
      for (int c = 0; c < 8; ++c) {
        float w0 = ((const float*)&wv[0][0])[c];
        float w1 = ((const float*)&wv[1][0])[c];
        float w2 = ((const float*)&wv[2][0])[c];
#pragma unroll
        for (int p = 0; p < 4; ++p) {
          float a0 = ((const float*)&xa[p + 0][0])[c] + w0;
          float a1 = ((const float*)&xa[p + 1][0])[c] + w1;
          float a2 = ((const float*)&xa[p + 2][0])[c] + w2;
          mx[p] = fmaxf(mx[p], fmaxf(a0, fmaxf(a1, a2)));
          mn[p] = fminf(mn[p], fminf(a0, fminf(a1, a2)));
        }
      }
    }
  }

  // ---- epilogue: lanes f consecutive -> coalesced 256 B stores ----
  float* ob = out + (((size_t)b * 30 + i) * 30 + j0) * 64 + f;
#pragma unroll
  for (int p = 0; p < 4; ++p)
    if (j0 + p < 30) ob[(size_t)p * 64] = mx[p] - mn[p] + bv;
}

extern "C" void kernel_launch(void* const* d_in, const int* in_sizes, int n_in,
                              void* d_out, int out_size, void* d_ws, size_t ws_size,
                              hipStream_t stream) {
  const float* x = (const float*)d_in[0];
  const float* w = (const float*)d_in[1];
  const float* bias = (const float*)d_in[2];
  float* out = (float*)d_out;
  dim3 grid(30, 8);  // (row, batch) = 240 blocks, 8 waves each
  dim3 block(512);
  hipLaunchKernelGGL(trop_kernel, grid, block, 0, stream, x, w, bias, out);
}